// Round 17
// baseline (354.591 us; speedup 1.0000x reference)
//
#include <hip/hip_runtime.h>
#include <hip/hip_bf16.h>
#include <cstdint>

#define NLAT 4096
#define NQRY 16384
#define QPW  1      // queries per wave (R17: was 2 — finer blocks, 2048-block grid)
#define WPB  8      // waves per block (independent; each owns an LDS slice)

// R12-proven fence: full lgkm drain. R16 A/B showed the drain is FASTER than
// a compiler-only fence (273.6 vs 295us) — the drain creates clean wave-yield
// points. R14 showed removing fences entirely spills (live-range explosion).
#define WSYNC() asm volatile("s_waitcnt lgkmcnt(0)" ::: "memory")

typedef __attribute__((ext_vector_type(8))) short bh8;    // 8 bf16 (4 VGPRs)
typedef __attribute__((ext_vector_type(4))) float f32x4;  // 4 fp32 acc

union FI { int i[4]; int4 q; bh8 v; };

// ---------------------------------------------------------------------------
// PINNED fp32 arithmetic (R6): every output-affecting op is an explicit
// rounded intrinsic -> output bits invariant to codegen/structural changes.
// ---------------------------------------------------------------------------

__device__ __forceinline__ float gelu_fast(float x) {
    float x3 = __fmul_rn(__fmul_rn(x, x), x);
    float s  = __fadd_rn(x, __fmul_rn(0.044715f, x3));
    float u2 = __fmul_rn(1.5957691216057308f, s);
    float e  = __expf(u2);
    float r  = __builtin_amdgcn_rcpf(__fadd_rn(e, 1.0f));
    return __fmul_rn(x, __fsub_rn(1.0f, r));
}
__device__ __forceinline__ float gelu_prec(float x) {
    float x3 = __fmul_rn(__fmul_rn(x, x), x);
    float s  = __fadd_rn(x, __fmul_rn(0.044715f, x3));
    float u2 = __fmul_rn(1.5957691216057308f, s);
    float e  = expf(u2);
    return __fmul_rn(x, __fdiv_rn(e, __fadd_rn(e, 1.0f)));
}

// pack bf16-truncations of (a -> low short, b -> high short) — exact bit-op
__device__ __forceinline__ int pk(float a, float b) {
    return (int)__builtin_amdgcn_perm(__float_as_uint(b), __float_as_uint(a), 0x07060302u);
}
__device__ __forceinline__ float mask16(float x) {
    return __uint_as_float(__float_as_uint(x) & 0xFFFF0000u);
}

// ---------------------------------------------------------------------------
// LDS tile: 16 rows x 64 f32 cols, XOR-swizzled (R12: bank conflicts = 0).
// dword addr = row*64 + (((col>>2) ^ row) & 15)*4 + (col&3)
// ---------------------------------------------------------------------------

// hi/lo A-fragments from swizzled f32 LDS tile (exact splits)
__device__ __forceinline__ void make_afrags(const float* sh, int lane, FI ah[2], FI al[2]) {
    const int m = lane & 15, quad = lane >> 4;
#pragma unroll
    for (int ks = 0; ks < 2; ks++) {
        const int g0 = ks * 8 + quad * 2;          // 4-dword group indices
        float4 v0 = *(const float4*)(sh + m * 64 + (((g0    ) ^ m) & 15) * 4);
        float4 v1 = *(const float4*)(sh + m * 64 + (((g0 + 1) ^ m) & 15) * 4);
        float x[8] = {v0.x, v0.y, v0.z, v0.w, v1.x, v1.y, v1.z, v1.w};
#pragma unroll
        for (int jj = 0; jj < 4; jj++) {
            float a = x[2 * jj], b = x[2 * jj + 1];
            ah[ks].i[jj] = pk(a, b);
            float la = __fsub_rn(a, mask16(a));   // exact
            float lb = __fsub_rn(b, mask16(b));
            al[ks].i[jj] = pk(la, lb);
        }
    }
}

// ---------------------------------------------------------------------------
// Prologue kernel: lb[v] = lower_bound(qry, v) for v in [0, NQRY].
// ---------------------------------------------------------------------------
__global__ __launch_bounds__(256) void build_bounds(
    const int* __restrict__ qry, int E, int* __restrict__ lb)
{
    int i = blockIdx.x * blockDim.x + threadIdx.x;
    if (i >= E) return;
    const int c = qry[i];
    const int p = (i == 0) ? -1 : qry[i - 1];
    for (int v = p + 1; v <= c; ++v) lb[v] = i;
    if (i == E - 1)
        for (int v = c + 1; v <= NQRY; ++v) lb[v] = E;
}

// min-waves=2: VGPR cap 256 -> natural demand ~108, no spill (min=4 forces a
// 64-VGPR target and catastrophic scratch traffic: R3/R7).
__global__ __launch_bounds__(WPB * 64, 2) void fused_kernel(
    const float* __restrict__ lat,  const float* __restrict__ rnd,
    const float* __restrict__ qc,
    const int* __restrict__ src0, const int* __restrict__ cnt0,
    const int* __restrict__ src1, const int* __restrict__ cnt1,
    const float* __restrict__ Wk0, const float* __restrict__ bk0,
    const float* __restrict__ Wk1, const float* __restrict__ bk1,
    const float* __restrict__ Wk2, const float* __restrict__ bk2,
    const float* __restrict__ Wsw0, const float* __restrict__ bsw0,
    const float* __restrict__ Wsw1, const float* __restrict__ bsw1,
    const float* __restrict__ Wp0, const float* __restrict__ bp0,
    const float* __restrict__ Wp1, const float* __restrict__ bp1,
    float* __restrict__ out)
{
    const int lane = threadIdx.x & 63;
    const int wid  = threadIdx.x >> 6;
    const int m16  = lane & 15;
    const int quad = lane >> 4;
    const int lg   = lane >> 2, lb2 = lane & 3;   // col=lane swizzle parts
    const int mg   = m16 >> 2,  mb2 = m16 & 3;    // col=16nt+m16 swizzle parts

    // LDS: 8 waves x 16x64 f32 tile (32768) + shared weight frags (16384)
    // = 49152 B static (+16K toolchain overhead -> 65536 reported, R12).
    __shared__ __align__(16) float sh_all[WPB][16 * 64];
    __shared__ __align__(16) int4  wlds[2][2][4][2][64];
    float* __restrict__ sh = sh_all[wid];

    // ---- W1/W2 hi/lo B-fragments -> LDS, built once by wave 0 ----
    if (wid == 0) {
        const float* Wmat[2] = {Wk1, Wk2};
#pragma unroll
        for (int L = 0; L < 2; L++)
#pragma unroll
            for (int ks = 0; ks < 2; ks++)
#pragma unroll
                for (int nt = 0; nt < 4; nt++) {
                    FI fh, fl;
#pragma unroll
                    for (int jj = 0; jj < 4; jj++) {
                        int k0 = ks * 32 + quad * 8 + 2 * jj;
                        float a = Wmat[L][(size_t)k0 * 64 + nt * 16 + m16];
                        float b = Wmat[L][(size_t)(k0 + 1) * 64 + nt * 16 + m16];
                        fh.i[jj] = pk(a, b);
                        float la = __fsub_rn(a, mask16(a));
                        float lb = __fsub_rn(b, mask16(b));
                        fl.i[jj] = pk(la, lb);
                    }
                    wlds[L][ks][nt][0][lane] = fh.q;
                    wlds[L][ks][nt][1][lane] = fl.q;
                }
    }

    // layer-1 weights (channel-per-lane), layer-2/3 bias per nt-tile
    const float w00 = Wk0[0 * 64 + lane];
    const float w01 = Wk0[1 * 64 + lane];
    const float w02 = Wk0[2 * 64 + lane];
    const float w03 = Wk0[3 * 64 + lane];
    const float b0  = bk0[lane];
    float b1v[4], b2v[4];
#pragma unroll
    for (int nt = 0; nt < 4; nt++) {
        b1v[nt] = bk1[16 * nt + m16];
        b2v[nt] = bk2[16 * nt + m16];
    }

    __syncthreads();   // cross-wave: wlds visible to all waves (once per kernel)

    // ---- segment bounds: direct lookup from precomputed tables ----
    // lanes [0..QPW]: cnt0[qbase+lane]; lanes [QPW+1..2QPW+1]: cnt1[...]
    const int qbase = (blockIdx.x * WPB + wid) * QPW;
    int bs = 0;
    if (lane <= QPW)              bs = cnt0[qbase + lane];
    else if (lane <= 2 * QPW + 1) bs = cnt1[qbase + lane - (QPW + 1)];

    for (int qi = 0; qi < QPW; qi++) {
        const int q = qbase + qi;
        const float qc0 = qc[2 * q];
        const float qc1 = qc[2 * q + 1];

        const int lo0 = __shfl(bs, qi, 64);
        const int hi0 = __shfl(bs, qi + 1, 64);
        const int lo1 = __shfl(bs, QPW + 1 + qi, 64);
        const int hi1 = __shfl(bs, QPW + 2 + qi, 64);

        // preload FIRST tile's edge meta for BOTH sets
        int pS[2] = {0, 0}; float pl0[2] = {0.f, 0.f}, pl1[2] = {0.f, 0.f};
#pragma unroll
        for (int s = 0; s < 2; s++) {
            const int lo = s ? lo1 : lo0, hi = s ? hi1 : hi0;
            const int* sp = s ? src1 : src0;
            if (lo < hi) {
                int idx = lo + m16; if (idx >= hi) idx = hi - 1;
                pS[s]  = sp[idx];
                pl0[s] = lat[2 * pS[s]];
                pl1[s] = lat[2 * pS[s] + 1];
            }
        }

        float msum[2][4];

#pragma unroll
        for (int set = 0; set < 2; set++) {
            const int* __restrict__ srcp = set ? src1 : src0;
            const int lo = set ? lo1 : lo0;
            const int hi = set ? hi1 : hi0;
            float a0 = 0.f, a1 = 0.f, a2 = 0.f, a3 = 0.f;

            int curS = pS[set]; float curl0 = pl0[set], curl1 = pl1[set];

            for (int e0 = lo; e0 < hi; e0 += 16) {
                const int rem = min(16, hi - e0);

                // prefetch NEXT tile's edge meta
                int nS = 0; float nl0 = 0.f, nl1 = 0.f;
                if (e0 + 16 < hi) {
                    int idx = e0 + 16 + m16; if (idx >= hi) idx = hi - 1;
                    nS  = srcp[idx];
                    nl0 = lat[2 * nS];
                    nl1 = lat[2 * nS + 1];
                }

                // layer 1 (channel-per-lane) -> sh[e][lane] (swizzled); pinned
#pragma unroll
                for (int e = 0; e < 16; e++) {
                    float l0 = __shfl(curl0, e, 64);
                    float l1 = __shfl(curl1, e, 64);
                    float t  = __fmul_rn(l0, w00);
                    t = __fmaf_rn(l1,  w01, t);
                    t = __fmaf_rn(qc0, w02, t);
                    t = __fmaf_rn(qc1, w03, t);
                    t = __fadd_rn(t, b0);
                    sh[e * 64 + ((lg ^ e) & 15) * 4 + lb2] = gelu_fast(t);
                }
                WSYNC();                               // (b) H1 ready

                FI ah[2], al[2];
                make_afrags(sh, lane, ah, al);
                WSYNC();                               // (c) H1 reads done

                // layer 2: H2 = gelu(H1@W1 + b1) -> sh   (4-term hi/lo)
                __builtin_amdgcn_s_setprio(1);
#pragma unroll
                for (int nt = 0; nt < 4; nt++) {
                    f32x4 C = {0.f, 0.f, 0.f, 0.f};
#pragma unroll
                    for (int ks = 0; ks < 2; ks++) {
                        FI fh, fl;
                        fh.q = wlds[0][ks][nt][0][lane];
                        fl.q = wlds[0][ks][nt][1][lane];
                        C = __builtin_amdgcn_mfma_f32_16x16x32_bf16(ah[ks].v, fh.v, C, 0, 0, 0);
                        C = __builtin_amdgcn_mfma_f32_16x16x32_bf16(al[ks].v, fh.v, C, 0, 0, 0);
                        C = __builtin_amdgcn_mfma_f32_16x16x32_bf16(ah[ks].v, fl.v, C, 0, 0, 0);
                        C = __builtin_amdgcn_mfma_f32_16x16x32_bf16(al[ks].v, fl.v, C, 0, 0, 0);
                    }
#pragma unroll
                    for (int r = 0; r < 4; r++) {
                        const int row = quad * 4 + r;
                        sh[row * 64 + (((4 * nt + mg) ^ row) & 15) * 4 + mb2] =
                            gelu_fast(__fadd_rn(C[r], b1v[nt]));
                    }
                }
                __builtin_amdgcn_s_setprio(0);
                WSYNC();                               // (d) H2 ready

                // issue ALL 16 edges' rnd gathers NOW; layer-3 covers latency
                float rA[8][4], rB[8][4];
#pragma unroll
                for (int e = 0; e < 8; e++) {
                    const int s = __shfl(curS, e, 64);
                    const float* rp = rnd + (size_t)s * 64 + lane;
                    rA[e][0] = rp[0];
                    rA[e][1] = rp[(size_t)1 * NLAT * 64];
                    rA[e][2] = rp[(size_t)2 * NLAT * 64];
                    rA[e][3] = rp[(size_t)3 * NLAT * 64];
                }
#pragma unroll
                for (int e = 0; e < 8; e++) {
                    const int s = __shfl(curS, 8 + e, 64);
                    const float* rp = rnd + (size_t)s * 64 + lane;
                    rB[e][0] = rp[0];
                    rB[e][1] = rp[(size_t)1 * NLAT * 64];
                    rB[e][2] = rp[(size_t)2 * NLAT * 64];
                    rB[e][3] = rp[(size_t)3 * NLAT * 64];
                }

                make_afrags(sh, lane, ah, al);
                WSYNC();                               // (e) H2 reads done

                // layer 3: K = H2@W2 + b2 -> sh (4-term)
                __builtin_amdgcn_s_setprio(1);
#pragma unroll
                for (int nt = 0; nt < 4; nt++) {
                    f32x4 C = {0.f, 0.f, 0.f, 0.f};
#pragma unroll
                    for (int ks = 0; ks < 2; ks++) {
                        FI fh, fl;
                        fh.q = wlds[1][ks][nt][0][lane];
                        fl.q = wlds[1][ks][nt][1][lane];
                        C = __builtin_amdgcn_mfma_f32_16x16x32_bf16(ah[ks].v, fh.v, C, 0, 0, 0);
                        C = __builtin_amdgcn_mfma_f32_16x16x32_bf16(al[ks].v, fh.v, C, 0, 0, 0);
                        C = __builtin_amdgcn_mfma_f32_16x16x32_bf16(ah[ks].v, fl.v, C, 0, 0, 0);
                        C = __builtin_amdgcn_mfma_f32_16x16x32_bf16(al[ks].v, fl.v, C, 0, 0, 0);
                    }
#pragma unroll
                    for (int r = 0; r < 4; r++) {
                        const int row = quad * 4 + r;
                        sh[row * 64 + (((4 * nt + mg) ^ row) & 15) * 4 + mb2] =
                            __fadd_rn(C[r], b2v[nt]);
                    }
                }
                __builtin_amdgcn_s_setprio(0);
                WSYNC();                               // (f) k ready

                // kv for all 16 rows (zero-predicated past rem)
                float kvv[16];
#pragma unroll
                for (int e = 0; e < 16; e++) {
                    const float v = sh[e * 64 + ((lg ^ e) & 15) * 4 + lb2];
                    kvv[e] = (e < rem) ? v : 0.f;
                }

                // pinned scatter-add form: separate mul, then add
#pragma unroll
                for (int e = 0; e < 8; e++) {
                    a0 = __fadd_rn(a0, __fmul_rn(kvv[e], rA[e][0]));
                    a1 = __fadd_rn(a1, __fmul_rn(kvv[e], rA[e][1]));
                    a2 = __fadd_rn(a2, __fmul_rn(kvv[e], rA[e][2]));
                    a3 = __fadd_rn(a3, __fmul_rn(kvv[e], rA[e][3]));
                }
#pragma unroll
                for (int e = 0; e < 8; e++) {
                    a0 = __fadd_rn(a0, __fmul_rn(kvv[8 + e], rB[e][0]));
                    a1 = __fadd_rn(a1, __fmul_rn(kvv[8 + e], rB[e][1]));
                    a2 = __fadd_rn(a2, __fmul_rn(kvv[8 + e], rB[e][2]));
                    a3 = __fadd_rn(a3, __fmul_rn(kvv[8 + e], rB[e][3]));
                }
                WSYNC();                               // (a) sh reads done before next overwrite

                curS = nS; curl0 = nl0; curl1 = nl1;
            }

            // pinned mean: true fp32 division
            const float cntf = fmaxf((float)(hi - lo), 1.0f);
            msum[set][0] = __fdiv_rn(a0, cntf);
            msum[set][1] = __fdiv_rn(a1, cntf);
            msum[set][2] = __fdiv_rn(a2, cntf);
            msum[set][3] = __fdiv_rn(a3, cntf);
        }

        // ---- softmax gate (pinned) ----
        float z0a = 0.f, z1a = 0.f;
#pragma unroll
        for (int i = 0; i < 16; i++) {
            float t = __fmul_rn(qc0, Wsw0[i]);
            t = __fmaf_rn(qc1, Wsw0[16 + i], t);
            t = __fadd_rn(t, bsw0[i]);
            const float h = fmaxf(0.f, t);
            z0a = __fmaf_rn(h, Wsw1[i * 2 + 0], z0a);
            z1a = __fmaf_rn(h, Wsw1[i * 2 + 1], z1a);
        }
        const float z0 = __fadd_rn(z0a, bsw1[0]);
        const float z1 = __fadd_rn(z1a, bsw1[1]);
        const float zm = fmaxf(z0, z1);
        const float e0s = expf(__fsub_rn(z0, zm)), e1s = expf(__fsub_rn(z1, zm));
        const float s01 = __fadd_rn(e0s, e1s);
        const float g0 = __fdiv_rn(e0s, s01), g1 = __fdiv_rn(e1s, s01);

        // decs ALIASED onto sh[0..255] (tile dead until next query's L1);
        // linear addressing in this phase (both write & read agree).
        WSYNC();                         // prior sh reads done
#pragma unroll
        for (int b = 0; b < 4; b++)
            sh[b * 64 + lane] = __fadd_rn(__fmul_rn(g0, msum[0][b]),
                                          __fmul_rn(g1, msum[1][b]));
        WSYNC();                         // decs ready

        // ---- projection: lane owns hidden cols 4*lane..4*lane+3 (pinned) ----
        float hacc[4][4];
#pragma unroll
        for (int t = 0; t < 4; t++)
#pragma unroll
            for (int b = 0; b < 4; b++) hacc[t][b] = 0.f;
#pragma unroll 8
        for (int c = 0; c < 64; c++) {
            const float4 w = ((const float4*)Wp0)[c * 64 + lane];
            const float wf[4] = { w.x, w.y, w.z, w.w };
            const float d0 = sh[0 * 64 + c], d1 = sh[1 * 64 + c];
            const float d2 = sh[2 * 64 + c], d3 = sh[3 * 64 + c];
#pragma unroll
            for (int t = 0; t < 4; t++) {
                hacc[t][0] = __fmaf_rn(wf[t], d0, hacc[t][0]);
                hacc[t][1] = __fmaf_rn(wf[t], d1, hacc[t][1]);
                hacc[t][2] = __fmaf_rn(wf[t], d2, hacc[t][2]);
                hacc[t][3] = __fmaf_rn(wf[t], d3, hacc[t][3]);
            }
        }
        {
            const float4 bv = ((const float4*)bp0)[lane];
            const float bt[4] = { bv.x, bv.y, bv.z, bv.w };
#pragma unroll
            for (int t = 0; t < 4; t++)
#pragma unroll
                for (int b = 0; b < 4; b++)
                    hacc[t][b] = gelu_prec(__fadd_rn(hacc[t][b], bt[t]));
        }

        float po[4][4];
#pragma unroll
        for (int b = 0; b < 4; b++)
#pragma unroll
            for (int k = 0; k < 4; k++) po[b][k] = 0.f;
#pragma unroll
        for (int t = 0; t < 4; t++) {
            const float4 w = ((const float4*)Wp1)[4 * lane + t];
            const float wf[4] = { w.x, w.y, w.z, w.w };
#pragma unroll
            for (int k = 0; k < 4; k++)
#pragma unroll
                for (int b = 0; b < 4; b++)
                    po[b][k] = __fmaf_rn(hacc[t][b], wf[k], po[b][k]);
        }
#pragma unroll
        for (int b = 0; b < 4; b++)
#pragma unroll
            for (int k = 0; k < 4; k++) {
                float v = po[b][k];
#pragma unroll
                for (int off = 32; off >= 1; off >>= 1)
                    v = __fadd_rn(v, __shfl_xor(v, off, 64));
                po[b][k] = v;
            }

        if (lane == 0) {
#pragma unroll
            for (int b = 0; b < 4; b++)
#pragma unroll
                for (int k = 0; k < 4; k++)
                    out[((size_t)b * NQRY + q) * 4 + k] = __fadd_rn(po[b][k], bp1[k]);
        }
        WSYNC();                         // protect decs region before next query's L1
    }
}

// ---------------------------------------------------------------------------
extern "C" void kernel_launch(void* const* d_in, const int* in_sizes, int n_in,
                              void* d_out, int out_size, void* d_ws, size_t ws_size,
                              hipStream_t stream) {
    const float* lat  = (const float*)d_in[0];
    const float* rnd  = (const float*)d_in[1];
    const float* qc   = (const float*)d_in[2];
    const int*   src0 = (const int*)d_in[3];
    const int*   qry0 = (const int*)d_in[4];
    const int*   src1 = (const int*)d_in[5];
    const int*   qry1 = (const int*)d_in[6];
    const float* Wk0 = (const float*)d_in[7],  *bk0 = (const float*)d_in[8];
    const float* Wk1 = (const float*)d_in[9],  *bk1 = (const float*)d_in[10];
    const float* Wk2 = (const float*)d_in[11], *bk2 = (const float*)d_in[12];
    const float* Wsw0 = (const float*)d_in[13], *bsw0 = (const float*)d_in[14];
    const float* Wsw1 = (const float*)d_in[15], *bsw1 = (const float*)d_in[16];
    const float* Wp0 = (const float*)d_in[17], *bp0 = (const float*)d_in[18];
    const float* Wp1 = (const float*)d_in[19], *bp1 = (const float*)d_in[20];

    const int E0 = in_sizes[3];
    const int E1 = in_sizes[5];

    // workspace: two bounds tables (lower_bound of every query id), 131080 B
    int* cnt0 = (int*)d_ws;
    int* cnt1 = cnt0 + (NQRY + 1);

    build_bounds<<<(E0 + 255) / 256, 256, 0, stream>>>(qry0, E0, cnt0);
    build_bounds<<<(E1 + 255) / 256, 256, 0, stream>>>(qry1, E1, cnt1);

    fused_kernel<<<NQRY / (QPW * WPB), WPB * 64, 0, stream>>>(
        lat, rnd, qc, src0, cnt0, src1, cnt1,
        Wk0, bk0, Wk1, bk1, Wk2, bk2,
        Wsw0, bsw0, Wsw1, bsw1, Wp0, bp0, Wp1, bp1,
        (float*)d_out);
}

// Round 18
// 334.028 us; speedup vs baseline: 1.0616x; 1.0616x over previous
//
#include <hip/hip_runtime.h>
#include <hip/hip_bf16.h>
#include <cstdint>

#define NLAT 4096
#define NQRY 16384
#define QPW  2      // queries per wave (R12-proven; QPW=1 regressed +6% in R17)
#define WPB  8      // waves per block (independent; each owns an LDS slice)

// R12-proven fence: full lgkm drain. R16 A/B: drain FASTER than compiler-only
// fence (273.6 vs 295us). R14: removing fences entirely spills (600us).
#define WSYNC() asm volatile("s_waitcnt lgkmcnt(0)" ::: "memory")

typedef __attribute__((ext_vector_type(8))) short bh8;    // 8 bf16 (4 VGPRs)
typedef __attribute__((ext_vector_type(4))) float f32x4;  // 4 fp32 acc

union FI { int i[4]; int4 q; bh8 v; };

// R18: constant-lane broadcast via v_readlane (VALU->SGPR) instead of __shfl
// (ds_bpermute, lgkm pipe). Bit-identical value; removes ~48 lgkm ops/tile
// from the WSYNC drain path and gives scalar-base gather addressing.
__device__ __forceinline__ float rlane_f(float v, int l) {
    return __uint_as_float(__builtin_amdgcn_readlane(__float_as_uint(v), l));
}

// ---------------------------------------------------------------------------
// PINNED fp32 arithmetic (R6): every output-affecting op is an explicit
// rounded intrinsic -> output bits invariant to codegen/structural changes.
// ---------------------------------------------------------------------------

__device__ __forceinline__ float gelu_fast(float x) {
    float x3 = __fmul_rn(__fmul_rn(x, x), x);
    float s  = __fadd_rn(x, __fmul_rn(0.044715f, x3));
    float u2 = __fmul_rn(1.5957691216057308f, s);
    float e  = __expf(u2);
    float r  = __builtin_amdgcn_rcpf(__fadd_rn(e, 1.0f));
    return __fmul_rn(x, __fsub_rn(1.0f, r));
}
__device__ __forceinline__ float gelu_prec(float x) {
    float x3 = __fmul_rn(__fmul_rn(x, x), x);
    float s  = __fadd_rn(x, __fmul_rn(0.044715f, x3));
    float u2 = __fmul_rn(1.5957691216057308f, s);
    float e  = expf(u2);
    return __fmul_rn(x, __fdiv_rn(e, __fadd_rn(e, 1.0f)));
}

// pack bf16-truncations of (a -> low short, b -> high short) — exact bit-op
__device__ __forceinline__ int pk(float a, float b) {
    return (int)__builtin_amdgcn_perm(__float_as_uint(b), __float_as_uint(a), 0x07060302u);
}
__device__ __forceinline__ float mask16(float x) {
    return __uint_as_float(__float_as_uint(x) & 0xFFFF0000u);
}

// ---------------------------------------------------------------------------
// LDS tile: 16 rows x 64 f32 cols, XOR-swizzled (R12: bank conflicts = 0).
// dword addr = row*64 + (((col>>2) ^ row) & 15)*4 + (col&3)
// ---------------------------------------------------------------------------

// hi/lo A-fragments from swizzled f32 LDS tile (exact splits)
__device__ __forceinline__ void make_afrags(const float* sh, int lane, FI ah[2], FI al[2]) {
    const int m = lane & 15, quad = lane >> 4;
#pragma unroll
    for (int ks = 0; ks < 2; ks++) {
        const int g0 = ks * 8 + quad * 2;          // 4-dword group indices
        float4 v0 = *(const float4*)(sh + m * 64 + (((g0    ) ^ m) & 15) * 4);
        float4 v1 = *(const float4*)(sh + m * 64 + (((g0 + 1) ^ m) & 15) * 4);
        float x[8] = {v0.x, v0.y, v0.z, v0.w, v1.x, v1.y, v1.z, v1.w};
#pragma unroll
        for (int jj = 0; jj < 4; jj++) {
            float a = x[2 * jj], b = x[2 * jj + 1];
            ah[ks].i[jj] = pk(a, b);
            float la = __fsub_rn(a, mask16(a));   // exact
            float lb = __fsub_rn(b, mask16(b));
            al[ks].i[jj] = pk(la, lb);
        }
    }
}

// ---------------------------------------------------------------------------
// Prologue kernel: lb[v] = lower_bound(qry, v) for v in [0, NQRY].
// ---------------------------------------------------------------------------
__global__ __launch_bounds__(256) void build_bounds(
    const int* __restrict__ qry, int E, int* __restrict__ lb)
{
    int i = blockIdx.x * blockDim.x + threadIdx.x;
    if (i >= E) return;
    const int c = qry[i];
    const int p = (i == 0) ? -1 : qry[i - 1];
    for (int v = p + 1; v <= c; ++v) lb[v] = i;
    if (i == E - 1)
        for (int v = c + 1; v <= NQRY; ++v) lb[v] = E;
}

// min-waves=2: VGPR cap 256 -> natural demand ~108, no spill (min=4 forces a
// 64-VGPR target and catastrophic scratch traffic: R3/R7).
__global__ __launch_bounds__(WPB * 64, 2) void fused_kernel(
    const float* __restrict__ lat,  const float* __restrict__ rnd,
    const float* __restrict__ qc,
    const int* __restrict__ src0, const int* __restrict__ cnt0,
    const int* __restrict__ src1, const int* __restrict__ cnt1,
    const float* __restrict__ Wk0, const float* __restrict__ bk0,
    const float* __restrict__ Wk1, const float* __restrict__ bk1,
    const float* __restrict__ Wk2, const float* __restrict__ bk2,
    const float* __restrict__ Wsw0, const float* __restrict__ bsw0,
    const float* __restrict__ Wsw1, const float* __restrict__ bsw1,
    const float* __restrict__ Wp0, const float* __restrict__ bp0,
    const float* __restrict__ Wp1, const float* __restrict__ bp1,
    float* __restrict__ out)
{
    const int lane = threadIdx.x & 63;
    const int wid  = threadIdx.x >> 6;
    const int m16  = lane & 15;
    const int quad = lane >> 4;
    const int lg   = lane >> 2, lb2 = lane & 3;   // col=lane swizzle parts
    const int mg   = m16 >> 2,  mb2 = m16 & 3;    // col=16nt+m16 swizzle parts

    // LDS: 8 waves x 16x64 f32 tile (32768) + shared weight frags (16384)
    // = 49152 B static (+16K toolchain overhead -> 65536 reported, R12).
    __shared__ __align__(16) float sh_all[WPB][16 * 64];
    __shared__ __align__(16) int4  wlds[2][2][4][2][64];
    float* __restrict__ sh = sh_all[wid];

    // ---- W1/W2 hi/lo B-fragments -> LDS, built once by wave 0 ----
    if (wid == 0) {
        const float* Wmat[2] = {Wk1, Wk2};
#pragma unroll
        for (int L = 0; L < 2; L++)
#pragma unroll
            for (int ks = 0; ks < 2; ks++)
#pragma unroll
                for (int nt = 0; nt < 4; nt++) {
                    FI fh, fl;
#pragma unroll
                    for (int jj = 0; jj < 4; jj++) {
                        int k0 = ks * 32 + quad * 8 + 2 * jj;
                        float a = Wmat[L][(size_t)k0 * 64 + nt * 16 + m16];
                        float b = Wmat[L][(size_t)(k0 + 1) * 64 + nt * 16 + m16];
                        fh.i[jj] = pk(a, b);
                        float la = __fsub_rn(a, mask16(a));
                        float lb = __fsub_rn(b, mask16(b));
                        fl.i[jj] = pk(la, lb);
                    }
                    wlds[L][ks][nt][0][lane] = fh.q;
                    wlds[L][ks][nt][1][lane] = fl.q;
                }
    }

    // layer-1 weights (channel-per-lane), layer-2/3 bias per nt-tile
    const float w00 = Wk0[0 * 64 + lane];
    const float w01 = Wk0[1 * 64 + lane];
    const float w02 = Wk0[2 * 64 + lane];
    const float w03 = Wk0[3 * 64 + lane];
    const float b0  = bk0[lane];
    float b1v[4], b2v[4];
#pragma unroll
    for (int nt = 0; nt < 4; nt++) {
        b1v[nt] = bk1[16 * nt + m16];
        b2v[nt] = bk2[16 * nt + m16];
    }

    __syncthreads();   // cross-wave: wlds visible to all waves (once per kernel)

    // ---- segment bounds: direct lookup from precomputed tables ----
    const int qbase = (blockIdx.x * WPB + wid) * QPW;
    int bs = 0;
    if (lane < 3)      bs = cnt0[qbase + lane];
    else if (lane < 6) bs = cnt1[qbase + lane - 3];

    for (int qi = 0; qi < QPW; qi++) {
        const int q = qbase + qi;
        const float qc0 = qc[2 * q];
        const float qc1 = qc[2 * q + 1];

        const int lo0 = __shfl(bs, qi, 64),     hi0 = __shfl(bs, qi + 1, 64);
        const int lo1 = __shfl(bs, 3 + qi, 64), hi1 = __shfl(bs, 4 + qi, 64);

        // preload FIRST tile's edge meta for BOTH sets
        int pS[2] = {0, 0}; float pl0[2] = {0.f, 0.f}, pl1[2] = {0.f, 0.f};
#pragma unroll
        for (int s = 0; s < 2; s++) {
            const int lo = s ? lo1 : lo0, hi = s ? hi1 : hi0;
            const int* sp = s ? src1 : src0;
            if (lo < hi) {
                int idx = lo + m16; if (idx >= hi) idx = hi - 1;
                pS[s]  = sp[idx];
                pl0[s] = lat[2 * pS[s]];
                pl1[s] = lat[2 * pS[s] + 1];
            }
        }

        float msum[2][4];

#pragma unroll
        for (int set = 0; set < 2; set++) {
            const int* __restrict__ srcp = set ? src1 : src0;
            const int lo = set ? lo1 : lo0;
            const int hi = set ? hi1 : hi0;
            float a0 = 0.f, a1 = 0.f, a2 = 0.f, a3 = 0.f;

            int curS = pS[set]; float curl0 = pl0[set], curl1 = pl1[set];

            for (int e0 = lo; e0 < hi; e0 += 16) {
                const int rem = min(16, hi - e0);

                // prefetch NEXT tile's edge meta
                int nS = 0; float nl0 = 0.f, nl1 = 0.f;
                if (e0 + 16 < hi) {
                    int idx = e0 + 16 + m16; if (idx >= hi) idx = hi - 1;
                    nS  = srcp[idx];
                    nl0 = lat[2 * nS];
                    nl1 = lat[2 * nS + 1];
                }

                // layer 1 (channel-per-lane) -> sh[e][lane] (swizzled); pinned.
                // R18: readlane broadcast (VALU) instead of shfl (lgkm).
#pragma unroll
                for (int e = 0; e < 16; e++) {
                    float l0 = rlane_f(curl0, e);
                    float l1 = rlane_f(curl1, e);
                    float t  = __fmul_rn(l0, w00);
                    t = __fmaf_rn(l1,  w01, t);
                    t = __fmaf_rn(qc0, w02, t);
                    t = __fmaf_rn(qc1, w03, t);
                    t = __fadd_rn(t, b0);
                    sh[e * 64 + ((lg ^ e) & 15) * 4 + lb2] = gelu_fast(t);
                }
                WSYNC();                               // (b) H1 ready

                FI ah[2], al[2];
                make_afrags(sh, lane, ah, al);
                WSYNC();                               // (c) H1 reads done

                // layer 2: H2 = gelu(H1@W1 + b1) -> sh   (4-term hi/lo)
                __builtin_amdgcn_s_setprio(1);
#pragma unroll
                for (int nt = 0; nt < 4; nt++) {
                    f32x4 C = {0.f, 0.f, 0.f, 0.f};
#pragma unroll
                    for (int ks = 0; ks < 2; ks++) {
                        FI fh, fl;
                        fh.q = wlds[0][ks][nt][0][lane];
                        fl.q = wlds[0][ks][nt][1][lane];
                        C = __builtin_amdgcn_mfma_f32_16x16x32_bf16(ah[ks].v, fh.v, C, 0, 0, 0);
                        C = __builtin_amdgcn_mfma_f32_16x16x32_bf16(al[ks].v, fh.v, C, 0, 0, 0);
                        C = __builtin_amdgcn_mfma_f32_16x16x32_bf16(ah[ks].v, fl.v, C, 0, 0, 0);
                        C = __builtin_amdgcn_mfma_f32_16x16x32_bf16(al[ks].v, fl.v, C, 0, 0, 0);
                    }
#pragma unroll
                    for (int r = 0; r < 4; r++) {
                        const int row = quad * 4 + r;
                        sh[row * 64 + (((4 * nt + mg) ^ row) & 15) * 4 + mb2] =
                            gelu_fast(__fadd_rn(C[r], b1v[nt]));
                    }
                }
                __builtin_amdgcn_s_setprio(0);
                WSYNC();                               // (d) H2 ready

                // issue ALL 16 edges' rnd gathers NOW; layer-3 covers latency.
                // R18: readlane index -> SGPR base, scalar addressing.
                float rA[8][4], rB[8][4];
#pragma unroll
                for (int e = 0; e < 8; e++) {
                    const int s = __builtin_amdgcn_readlane(curS, e);
                    const float* rp = rnd + (size_t)s * 64 + lane;
                    rA[e][0] = rp[0];
                    rA[e][1] = rp[(size_t)1 * NLAT * 64];
                    rA[e][2] = rp[(size_t)2 * NLAT * 64];
                    rA[e][3] = rp[(size_t)3 * NLAT * 64];
                }
#pragma unroll
                for (int e = 0; e < 8; e++) {
                    const int s = __builtin_amdgcn_readlane(curS, 8 + e);
                    const float* rp = rnd + (size_t)s * 64 + lane;
                    rB[e][0] = rp[0];
                    rB[e][1] = rp[(size_t)1 * NLAT * 64];
                    rB[e][2] = rp[(size_t)2 * NLAT * 64];
                    rB[e][3] = rp[(size_t)3 * NLAT * 64];
                }

                make_afrags(sh, lane, ah, al);
                WSYNC();                               // (e) H2 reads done

                // layer 3: K = H2@W2 + b2 -> sh (4-term)
                __builtin_amdgcn_s_setprio(1);
#pragma unroll
                for (int nt = 0; nt < 4; nt++) {
                    f32x4 C = {0.f, 0.f, 0.f, 0.f};
#pragma unroll
                    for (int ks = 0; ks < 2; ks++) {
                        FI fh, fl;
                        fh.q = wlds[1][ks][nt][0][lane];
                        fl.q = wlds[1][ks][nt][1][lane];
                        C = __builtin_amdgcn_mfma_f32_16x16x32_bf16(ah[ks].v, fh.v, C, 0, 0, 0);
                        C = __builtin_amdgcn_mfma_f32_16x16x32_bf16(al[ks].v, fh.v, C, 0, 0, 0);
                        C = __builtin_amdgcn_mfma_f32_16x16x32_bf16(ah[ks].v, fl.v, C, 0, 0, 0);
                        C = __builtin_amdgcn_mfma_f32_16x16x32_bf16(al[ks].v, fl.v, C, 0, 0, 0);
                    }
#pragma unroll
                    for (int r = 0; r < 4; r++) {
                        const int row = quad * 4 + r;
                        sh[row * 64 + (((4 * nt + mg) ^ row) & 15) * 4 + mb2] =
                            __fadd_rn(C[r], b2v[nt]);
                    }
                }
                __builtin_amdgcn_s_setprio(0);
                WSYNC();                               // (f) k ready

                // kv for all 16 rows (zero-predicated past rem)
                float kvv[16];
#pragma unroll
                for (int e = 0; e < 16; e++) {
                    const float v = sh[e * 64 + ((lg ^ e) & 15) * 4 + lb2];
                    kvv[e] = (e < rem) ? v : 0.f;
                }

                // pinned scatter-add form: separate mul, then add
#pragma unroll
                for (int e = 0; e < 8; e++) {
                    a0 = __fadd_rn(a0, __fmul_rn(kvv[e], rA[e][0]));
                    a1 = __fadd_rn(a1, __fmul_rn(kvv[e], rA[e][1]));
                    a2 = __fadd_rn(a2, __fmul_rn(kvv[e], rA[e][2]));
                    a3 = __fadd_rn(a3, __fmul_rn(kvv[e], rA[e][3]));
                }
#pragma unroll
                for (int e = 0; e < 8; e++) {
                    a0 = __fadd_rn(a0, __fmul_rn(kvv[8 + e], rB[e][0]));
                    a1 = __fadd_rn(a1, __fmul_rn(kvv[8 + e], rB[e][1]));
                    a2 = __fadd_rn(a2, __fmul_rn(kvv[8 + e], rB[e][2]));
                    a3 = __fadd_rn(a3, __fmul_rn(kvv[8 + e], rB[e][3]));
                }
                WSYNC();                               // (a) sh reads done before next overwrite

                curS = nS; curl0 = nl0; curl1 = nl1;
            }

            // pinned mean: true fp32 division
            const float cntf = fmaxf((float)(hi - lo), 1.0f);
            msum[set][0] = __fdiv_rn(a0, cntf);
            msum[set][1] = __fdiv_rn(a1, cntf);
            msum[set][2] = __fdiv_rn(a2, cntf);
            msum[set][3] = __fdiv_rn(a3, cntf);
        }

        // ---- softmax gate (pinned) ----
        float z0a = 0.f, z1a = 0.f;
#pragma unroll
        for (int i = 0; i < 16; i++) {
            float t = __fmul_rn(qc0, Wsw0[i]);
            t = __fmaf_rn(qc1, Wsw0[16 + i], t);
            t = __fadd_rn(t, bsw0[i]);
            const float h = fmaxf(0.f, t);
            z0a = __fmaf_rn(h, Wsw1[i * 2 + 0], z0a);
            z1a = __fmaf_rn(h, Wsw1[i * 2 + 1], z1a);
        }
        const float z0 = __fadd_rn(z0a, bsw1[0]);
        const float z1 = __fadd_rn(z1a, bsw1[1]);
        const float zm = fmaxf(z0, z1);
        const float e0s = expf(__fsub_rn(z0, zm)), e1s = expf(__fsub_rn(z1, zm));
        const float s01 = __fadd_rn(e0s, e1s);
        const float g0 = __fdiv_rn(e0s, s01), g1 = __fdiv_rn(e1s, s01);

        // decs ALIASED onto sh[0..255] (tile dead until next query's L1);
        // linear addressing in this phase (both write & read agree).
        WSYNC();                         // prior sh reads done
#pragma unroll
        for (int b = 0; b < 4; b++)
            sh[b * 64 + lane] = __fadd_rn(__fmul_rn(g0, msum[0][b]),
                                          __fmul_rn(g1, msum[1][b]));
        WSYNC();                         // decs ready

        // ---- projection: lane owns hidden cols 4*lane..4*lane+3 (pinned) ----
        float hacc[4][4];
#pragma unroll
        for (int t = 0; t < 4; t++)
#pragma unroll
            for (int b = 0; b < 4; b++) hacc[t][b] = 0.f;
#pragma unroll 8
        for (int c = 0; c < 64; c++) {
            const float4 w = ((const float4*)Wp0)[c * 64 + lane];
            const float wf[4] = { w.x, w.y, w.z, w.w };
            const float d0 = sh[0 * 64 + c], d1 = sh[1 * 64 + c];
            const float d2 = sh[2 * 64 + c], d3 = sh[3 * 64 + c];
#pragma unroll
            for (int t = 0; t < 4; t++) {
                hacc[t][0] = __fmaf_rn(wf[t], d0, hacc[t][0]);
                hacc[t][1] = __fmaf_rn(wf[t], d1, hacc[t][1]);
                hacc[t][2] = __fmaf_rn(wf[t], d2, hacc[t][2]);
                hacc[t][3] = __fmaf_rn(wf[t], d3, hacc[t][3]);
            }
        }
        {
            const float4 bv = ((const float4*)bp0)[lane];
            const float bt[4] = { bv.x, bv.y, bv.z, bv.w };
#pragma unroll
            for (int t = 0; t < 4; t++)
#pragma unroll
                for (int b = 0; b < 4; b++)
                    hacc[t][b] = gelu_prec(__fadd_rn(hacc[t][b], bt[t]));
        }

        float po[4][4];
#pragma unroll
        for (int b = 0; b < 4; b++)
#pragma unroll
            for (int k = 0; k < 4; k++) po[b][k] = 0.f;
#pragma unroll
        for (int t = 0; t < 4; t++) {
            const float4 w = ((const float4*)Wp1)[4 * lane + t];
            const float wf[4] = { w.x, w.y, w.z, w.w };
#pragma unroll
            for (int k = 0; k < 4; k++)
#pragma unroll
                for (int b = 0; b < 4; b++)
                    po[b][k] = __fmaf_rn(hacc[t][b], wf[k], po[b][k]);
        }
#pragma unroll
        for (int b = 0; b < 4; b++)
#pragma unroll
            for (int k = 0; k < 4; k++) {
                float v = po[b][k];
#pragma unroll
                for (int off = 32; off >= 1; off >>= 1)
                    v = __fadd_rn(v, __shfl_xor(v, off, 64));
                po[b][k] = v;
            }

        if (lane == 0) {
#pragma unroll
            for (int b = 0; b < 4; b++)
#pragma unroll
                for (int k = 0; k < 4; k++)
                    out[((size_t)b * NQRY + q) * 4 + k] = __fadd_rn(po[b][k], bp1[k]);
        }
        WSYNC();                         // protect decs region before next query's L1
    }
}

// ---------------------------------------------------------------------------
extern "C" void kernel_launch(void* const* d_in, const int* in_sizes, int n_in,
                              void* d_out, int out_size, void* d_ws, size_t ws_size,
                              hipStream_t stream) {
    const float* lat  = (const float*)d_in[0];
    const float* rnd  = (const float*)d_in[1];
    const float* qc   = (const float*)d_in[2];
    const int*   src0 = (const int*)d_in[3];
    const int*   qry0 = (const int*)d_in[4];
    const int*   src1 = (const int*)d_in[5];
    const int*   qry1 = (const int*)d_in[6];
    const float* Wk0 = (const float*)d_in[7],  *bk0 = (const float*)d_in[8];
    const float* Wk1 = (const float*)d_in[9],  *bk1 = (const float*)d_in[10];
    const float* Wk2 = (const float*)d_in[11], *bk2 = (const float*)d_in[12];
    const float* Wsw0 = (const float*)d_in[13], *bsw0 = (const float*)d_in[14];
    const float* Wsw1 = (const float*)d_in[15], *bsw1 = (const float*)d_in[16];
    const float* Wp0 = (const float*)d_in[17], *bp0 = (const float*)d_in[18];
    const float* Wp1 = (const float*)d_in[19], *bp1 = (const float*)d_in[20];

    const int E0 = in_sizes[3];
    const int E1 = in_sizes[5];

    // workspace: two bounds tables (lower_bound of every query id), 131080 B
    int* cnt0 = (int*)d_ws;
    int* cnt1 = cnt0 + (NQRY + 1);

    build_bounds<<<(E0 + 255) / 256, 256, 0, stream>>>(qry0, E0, cnt0);
    build_bounds<<<(E1 + 255) / 256, 256, 0, stream>>>(qry1, E1, cnt1);

    fused_kernel<<<NQRY / (QPW * WPB), WPB * 64, 0, stream>>>(
        lat, rnd, qc, src0, cnt0, src1, cnt1,
        Wk0, bk0, Wk1, bk1, Wk2, bk2,
        Wsw0, bsw0, Wsw1, bsw1, Wp0, bp0, Wp1, bp1,
        (float*)d_out);
}

// Round 21
// 331.888 us; speedup vs baseline: 1.0684x; 1.0064x over previous
//
#include <hip/hip_runtime.h>
#include <hip/hip_bf16.h>
#include <cstdint>

#define NLAT 4096
#define NQRY 16384
#define QPW  2      // queries per wave (R12-proven; QPW=1 regressed +6% in R17)
#define WPB  8      // waves per block (independent; each owns an LDS slice)

// R12-proven fence: full lgkm drain. R16 A/B: drain FASTER than compiler-only
// fence (273.6 vs 295us). R14: removing fences entirely spills (600us).
#define WSYNC() asm volatile("s_waitcnt lgkmcnt(0)" ::: "memory")

typedef __attribute__((ext_vector_type(8))) short bh8;    // 8 bf16 (4 VGPRs)
typedef __attribute__((ext_vector_type(4))) float f32x4;  // 4 fp32 acc

union FI { int i[4]; int4 q; bh8 v; };

// R18: constant-lane broadcast via v_readlane (VALU->SGPR) instead of __shfl.
__device__ __forceinline__ float rlane_f(float v, int l) {
    return __uint_as_float(__builtin_amdgcn_readlane(__float_as_uint(v), l));
}

// ---------------------------------------------------------------------------
// PINNED fp32 arithmetic (R6): every output-affecting op is an explicit
// rounded intrinsic -> output bits invariant to codegen/structural changes.
// R19 re-roll (deterministic, one-time): L1 base hoist + fma accumulate.
// ---------------------------------------------------------------------------

__device__ __forceinline__ float gelu_fast(float x) {
    float x3 = __fmul_rn(__fmul_rn(x, x), x);
    float s  = __fadd_rn(x, __fmul_rn(0.044715f, x3));
    float u2 = __fmul_rn(1.5957691216057308f, s);
    float e  = __expf(u2);
    float r  = __builtin_amdgcn_rcpf(__fadd_rn(e, 1.0f));
    return __fmul_rn(x, __fsub_rn(1.0f, r));
}
__device__ __forceinline__ float gelu_prec(float x) {
    float x3 = __fmul_rn(__fmul_rn(x, x), x);
    float s  = __fadd_rn(x, __fmul_rn(0.044715f, x3));
    float u2 = __fmul_rn(1.5957691216057308f, s);
    float e  = expf(u2);
    return __fmul_rn(x, __fdiv_rn(e, __fadd_rn(e, 1.0f)));
}

// pack bf16-truncations of (a -> low short, b -> high short) — exact bit-op
__device__ __forceinline__ int pk(float a, float b) {
    return (int)__builtin_amdgcn_perm(__float_as_uint(b), __float_as_uint(a), 0x07060302u);
}
__device__ __forceinline__ float mask16(float x) {
    return __uint_as_float(__float_as_uint(x) & 0xFFFF0000u);
}

// ---------------------------------------------------------------------------
// LDS tile: 16 rows x 64 f32 cols, XOR-swizzled (R12: bank conflicts = 0).
// dword addr = row*64 + (((col>>2) ^ row) & 15)*4 + (col&3)
// ---------------------------------------------------------------------------

// hi/lo A-fragments from swizzled f32 LDS tile (exact splits)
__device__ __forceinline__ void make_afrags(const float* sh, int lane, FI ah[2], FI al[2]) {
    const int m = lane & 15, quad = lane >> 4;
#pragma unroll
    for (int ks = 0; ks < 2; ks++) {
        const int g0 = ks * 8 + quad * 2;          // 4-dword group indices
        float4 v0 = *(const float4*)(sh + m * 64 + (((g0    ) ^ m) & 15) * 4);
        float4 v1 = *(const float4*)(sh + m * 64 + (((g0 + 1) ^ m) & 15) * 4);
        float x[8] = {v0.x, v0.y, v0.z, v0.w, v1.x, v1.y, v1.z, v1.w};
#pragma unroll
        for (int jj = 0; jj < 4; jj++) {
            float a = x[2 * jj], b = x[2 * jj + 1];
            ah[ks].i[jj] = pk(a, b);
            float la = __fsub_rn(a, mask16(a));   // exact
            float lb = __fsub_rn(b, mask16(b));
            al[ks].i[jj] = pk(la, lb);
        }
    }
}

// ---------------------------------------------------------------------------
// Prologue kernel: lb[v] = lower_bound(qry, v) for v in [0, NQRY].
// ---------------------------------------------------------------------------
__global__ __launch_bounds__(256) void build_bounds(
    const int* __restrict__ qry, int E, int* __restrict__ lb)
{
    int i = blockIdx.x * blockDim.x + threadIdx.x;
    if (i >= E) return;
    const int c = qry[i];
    const int p = (i == 0) ? -1 : qry[i - 1];
    for (int v = p + 1; v <= c; ++v) lb[v] = i;
    if (i == E - 1)
        for (int v = c + 1; v <= NQRY; ++v) lb[v] = E;
}

// min-waves=2: VGPR cap 256 -> natural demand ~100, no spill (min=4 forces a
// 64-VGPR target and catastrophic scratch traffic: R3/R7).
__global__ __launch_bounds__(WPB * 64, 2) void fused_kernel(
    const float* __restrict__ lat,  const float* __restrict__ rnd,
    const float* __restrict__ qc,
    const int* __restrict__ src0, const int* __restrict__ cnt0,
    const int* __restrict__ src1, const int* __restrict__ cnt1,
    const float* __restrict__ Wk0, const float* __restrict__ bk0,
    const float* __restrict__ Wk1, const float* __restrict__ bk1,
    const float* __restrict__ Wk2, const float* __restrict__ bk2,
    const float* __restrict__ Wsw0, const float* __restrict__ bsw0,
    const float* __restrict__ Wsw1, const float* __restrict__ bsw1,
    const float* __restrict__ Wp0, const float* __restrict__ bp0,
    const float* __restrict__ Wp1, const float* __restrict__ bp1,
    float* __restrict__ out)
{
    const int lane = threadIdx.x & 63;
    const int wid  = threadIdx.x >> 6;
    const int m16  = lane & 15;
    const int quad = lane >> 4;
    const int lg   = lane >> 2, lb2 = lane & 3;   // col=lane swizzle parts
    const int mg   = m16 >> 2,  mb2 = m16 & 3;    // col=16nt+m16 swizzle parts

    // LDS: 8 waves x 16x64 f32 tile (32768) + shared weight frags (16384)
    // = 49152 B static (+16K toolchain overhead -> 65536 reported, R12).
    __shared__ __align__(16) float sh_all[WPB][16 * 64];
    __shared__ __align__(16) int4  wlds[2][2][4][2][64];
    float* __restrict__ sh = sh_all[wid];

    // ---- W1/W2 hi/lo B-fragments -> LDS, built once by wave 0 ----
    if (wid == 0) {
        const float* Wmat[2] = {Wk1, Wk2};
#pragma unroll
        for (int L = 0; L < 2; L++)
#pragma unroll
            for (int ks = 0; ks < 2; ks++)
#pragma unroll
                for (int nt = 0; nt < 4; nt++) {
                    FI fh, fl;
#pragma unroll
                    for (int jj = 0; jj < 4; jj++) {
                        int k0 = ks * 32 + quad * 8 + 2 * jj;
                        float a = Wmat[L][(size_t)k0 * 64 + nt * 16 + m16];
                        float b = Wmat[L][(size_t)(k0 + 1) * 64 + nt * 16 + m16];
                        fh.i[jj] = pk(a, b);
                        float la = __fsub_rn(a, mask16(a));
                        float lb = __fsub_rn(b, mask16(b));
                        fl.i[jj] = pk(la, lb);
                    }
                    wlds[L][ks][nt][0][lane] = fh.q;
                    wlds[L][ks][nt][1][lane] = fl.q;
                }
    }

    // layer-1 weights (channel-per-lane), layer-2/3 bias per nt-tile
    const float w00 = Wk0[0 * 64 + lane];
    const float w01 = Wk0[1 * 64 + lane];
    const float w02 = Wk0[2 * 64 + lane];
    const float w03 = Wk0[3 * 64 + lane];
    const float b0  = bk0[lane];
    float b1v[4], b2v[4];
#pragma unroll
    for (int nt = 0; nt < 4; nt++) {
        b1v[nt] = bk1[16 * nt + m16];
        b2v[nt] = bk2[16 * nt + m16];
    }

    __syncthreads();   // cross-wave: wlds visible to all waves (once per kernel)

    // ---- segment bounds: direct lookup from precomputed tables ----
    const int qbase = (blockIdx.x * WPB + wid) * QPW;
    int bs = 0;
    if (lane < 3)      bs = cnt0[qbase + lane];
    else if (lane < 6) bs = cnt1[qbase + lane - 3];

    for (int qi = 0; qi < QPW; qi++) {
        const int q = qbase + qi;
        const float qc0 = qc[2 * q];
        const float qc1 = qc[2 * q + 1];

        // R19: loop-invariant L1 base hoist (pinned): b0 + qc0*w02 + qc1*w03
        const float base0 = __fmaf_rn(qc1, w03, __fmaf_rn(qc0, w02, b0));

        const int lo0 = __shfl(bs, qi, 64),     hi0 = __shfl(bs, qi + 1, 64);
        const int lo1 = __shfl(bs, 3 + qi, 64), hi1 = __shfl(bs, 4 + qi, 64);

        // preload FIRST tile's edge meta for BOTH sets
        int pS[2] = {0, 0}; float pl0[2] = {0.f, 0.f}, pl1[2] = {0.f, 0.f};
#pragma unroll
        for (int s = 0; s < 2; s++) {
            const int lo = s ? lo1 : lo0, hi = s ? hi1 : hi0;
            const int* sp = s ? src1 : src0;
            if (lo < hi) {
                int idx = lo + m16; if (idx >= hi) idx = hi - 1;
                pS[s]  = sp[idx];
                pl0[s] = lat[2 * pS[s]];
                pl1[s] = lat[2 * pS[s] + 1];
            }
        }

        float msum[2][4];

#pragma unroll
        for (int set = 0; set < 2; set++) {
            const int* __restrict__ srcp = set ? src1 : src0;
            const int lo = set ? lo1 : lo0;
            const int hi = set ? hi1 : hi0;
            float a0 = 0.f, a1 = 0.f, a2 = 0.f, a3 = 0.f;

            int curS = pS[set]; float curl0 = pl0[set], curl1 = pl1[set];

            for (int e0 = lo; e0 < hi; e0 += 16) {
                const int rem = min(16, hi - e0);

                // prefetch NEXT tile's edge meta
                int nS = 0; float nl0 = 0.f, nl1 = 0.f;
                if (e0 + 16 < hi) {
                    int idx = e0 + 16 + m16; if (idx >= hi) idx = hi - 1;
                    nS  = srcp[idx];
                    nl0 = lat[2 * nS];
                    nl1 = lat[2 * nS + 1];
                }

                // layer 1 (channel-per-lane) -> sh[e][lane] (swizzled); pinned.
                // R19: hoisted base0; 2 fma per edge instead of 1 mul + 4 fma/add.
#pragma unroll
                for (int e = 0; e < 16; e++) {
                    float l0 = rlane_f(curl0, e);
                    float l1 = rlane_f(curl1, e);
                    float t  = __fmaf_rn(l1, w01, __fmaf_rn(l0, w00, base0));
                    sh[e * 64 + ((lg ^ e) & 15) * 4 + lb2] = gelu_fast(t);
                }
                WSYNC();                               // (b) H1 ready

                FI ah[2], al[2];
                make_afrags(sh, lane, ah, al);
                WSYNC();                               // (c) H1 reads done

                // layer 2: H2 = gelu(H1@W1 + b1) -> sh   (4-term hi/lo)
                __builtin_amdgcn_s_setprio(1);
#pragma unroll
                for (int nt = 0; nt < 4; nt++) {
                    f32x4 C = {0.f, 0.f, 0.f, 0.f};
#pragma unroll
                    for (int ks = 0; ks < 2; ks++) {
                        FI fh, fl;
                        fh.q = wlds[0][ks][nt][0][lane];
                        fl.q = wlds[0][ks][nt][1][lane];
                        C = __builtin_amdgcn_mfma_f32_16x16x32_bf16(ah[ks].v, fh.v, C, 0, 0, 0);
                        C = __builtin_amdgcn_mfma_f32_16x16x32_bf16(al[ks].v, fh.v, C, 0, 0, 0);
                        C = __builtin_amdgcn_mfma_f32_16x16x32_bf16(ah[ks].v, fl.v, C, 0, 0, 0);
                        C = __builtin_amdgcn_mfma_f32_16x16x32_bf16(al[ks].v, fl.v, C, 0, 0, 0);
                    }
#pragma unroll
                    for (int r = 0; r < 4; r++) {
                        const int row = quad * 4 + r;
                        sh[row * 64 + (((4 * nt + mg) ^ row) & 15) * 4 + mb2] =
                            gelu_fast(__fadd_rn(C[r], b1v[nt]));
                    }
                }
                __builtin_amdgcn_s_setprio(0);
                WSYNC();                               // (d) H2 ready

                // issue ALL 16 edges' rnd gathers NOW; layer-3 covers latency.
                float rA[8][4], rB[8][4];
#pragma unroll
                for (int e = 0; e < 8; e++) {
                    const int s = __builtin_amdgcn_readlane(curS, e);
                    const float* rp = rnd + (size_t)s * 64 + lane;
                    rA[e][0] = rp[0];
                    rA[e][1] = rp[(size_t)1 * NLAT * 64];
                    rA[e][2] = rp[(size_t)2 * NLAT * 64];
                    rA[e][3] = rp[(size_t)3 * NLAT * 64];
                }
#pragma unroll
                for (int e = 0; e < 8; e++) {
                    const int s = __builtin_amdgcn_readlane(curS, 8 + e);
                    const float* rp = rnd + (size_t)s * 64 + lane;
                    rB[e][0] = rp[0];
                    rB[e][1] = rp[(size_t)1 * NLAT * 64];
                    rB[e][2] = rp[(size_t)2 * NLAT * 64];
                    rB[e][3] = rp[(size_t)3 * NLAT * 64];
                }

                make_afrags(sh, lane, ah, al);
                WSYNC();                               // (e) H2 reads done

                // layer 3: K = H2@W2 + b2 -> sh (4-term)
                __builtin_amdgcn_s_setprio(1);
#pragma unroll
                for (int nt = 0; nt < 4; nt++) {
                    f32x4 C = {0.f, 0.f, 0.f, 0.f};
#pragma unroll
                    for (int ks = 0; ks < 2; ks++) {
                        FI fh, fl;
                        fh.q = wlds[1][ks][nt][0][lane];
                        fl.q = wlds[1][ks][nt][1][lane];
                        C = __builtin_amdgcn_mfma_f32_16x16x32_bf16(ah[ks].v, fh.v, C, 0, 0, 0);
                        C = __builtin_amdgcn_mfma_f32_16x16x32_bf16(al[ks].v, fh.v, C, 0, 0, 0);
                        C = __builtin_amdgcn_mfma_f32_16x16x32_bf16(ah[ks].v, fl.v, C, 0, 0, 0);
                        C = __builtin_amdgcn_mfma_f32_16x16x32_bf16(al[ks].v, fl.v, C, 0, 0, 0);
                    }
#pragma unroll
                    for (int r = 0; r < 4; r++) {
                        const int row = quad * 4 + r;
                        sh[row * 64 + (((4 * nt + mg) ^ row) & 15) * 4 + mb2] =
                            __fadd_rn(C[r], b2v[nt]);
                    }
                }
                __builtin_amdgcn_s_setprio(0);
                WSYNC();                               // (f) k ready

                // kv for all 16 rows (zero-predicated past rem)
                float kvv[16];
#pragma unroll
                for (int e = 0; e < 16; e++) {
                    const float v = sh[e * 64 + ((lg ^ e) & 15) * 4 + lb2];
                    kvv[e] = (e < rem) ? v : 0.f;
                }

                // R19: pinned fma accumulate (64 ops/tile instead of 128,
                // tighter per-step rounding than mul-then-add)
#pragma unroll
                for (int e = 0; e < 8; e++) {
                    a0 = __fmaf_rn(kvv[e], rA[e][0], a0);
                    a1 = __fmaf_rn(kvv[e], rA[e][1], a1);
                    a2 = __fmaf_rn(kvv[e], rA[e][2], a2);
                    a3 = __fmaf_rn(kvv[e], rA[e][3], a3);
                }
#pragma unroll
                for (int e = 0; e < 8; e++) {
                    a0 = __fmaf_rn(kvv[8 + e], rB[e][0], a0);
                    a1 = __fmaf_rn(kvv[8 + e], rB[e][1], a1);
                    a2 = __fmaf_rn(kvv[8 + e], rB[e][2], a2);
                    a3 = __fmaf_rn(kvv[8 + e], rB[e][3], a3);
                }
                WSYNC();                               // (a) sh reads done before next overwrite

                curS = nS; curl0 = nl0; curl1 = nl1;
            }

            // pinned mean: true fp32 division
            const float cntf = fmaxf((float)(hi - lo), 1.0f);
            msum[set][0] = __fdiv_rn(a0, cntf);
            msum[set][1] = __fdiv_rn(a1, cntf);
            msum[set][2] = __fdiv_rn(a2, cntf);
            msum[set][3] = __fdiv_rn(a3, cntf);
        }

        // ---- softmax gate (pinned) ----
        float z0a = 0.f, z1a = 0.f;
#pragma unroll
        for (int i = 0; i < 16; i++) {
            float t = __fmul_rn(qc0, Wsw0[i]);
            t = __fmaf_rn(qc1, Wsw0[16 + i], t);
            t = __fadd_rn(t, bsw0[i]);
            const float h = fmaxf(0.f, t);
            z0a = __fmaf_rn(h, Wsw1[i * 2 + 0], z0a);
            z1a = __fmaf_rn(h, Wsw1[i * 2 + 1], z1a);
        }
        const float z0 = __fadd_rn(z0a, bsw1[0]);
        const float z1 = __fadd_rn(z1a, bsw1[1]);
        const float zm = fmaxf(z0, z1);
        const float e0s = expf(__fsub_rn(z0, zm)), e1s = expf(__fsub_rn(z1, zm));
        const float s01 = __fadd_rn(e0s, e1s);
        const float g0 = __fdiv_rn(e0s, s01), g1 = __fdiv_rn(e1s, s01);

        // decs ALIASED onto sh[0..255] (tile dead until next query's L1);
        // linear addressing in this phase (both write & read agree).
        WSYNC();                         // prior sh reads done
#pragma unroll
        for (int b = 0; b < 4; b++)
            sh[b * 64 + lane] = __fadd_rn(__fmul_rn(g0, msum[0][b]),
                                          __fmul_rn(g1, msum[1][b]));
        WSYNC();                         // decs ready

        // ---- projection: lane owns hidden cols 4*lane..4*lane+3 (pinned) ----
        float hacc[4][4];
#pragma unroll
        for (int t = 0; t < 4; t++)
#pragma unroll
            for (int b = 0; b < 4; b++) hacc[t][b] = 0.f;
#pragma unroll 8
        for (int c = 0; c < 64; c++) {
            const float4 w = ((const float4*)Wp0)[c * 64 + lane];
            const float wf[4] = { w.x, w.y, w.z, w.w };
            const float d0 = sh[0 * 64 + c], d1 = sh[1 * 64 + c];
            const float d2 = sh[2 * 64 + c], d3 = sh[3 * 64 + c];
#pragma unroll
            for (int t = 0; t < 4; t++) {
                hacc[t][0] = __fmaf_rn(wf[t], d0, hacc[t][0]);
                hacc[t][1] = __fmaf_rn(wf[t], d1, hacc[t][1]);
                hacc[t][2] = __fmaf_rn(wf[t], d2, hacc[t][2]);
                hacc[t][3] = __fmaf_rn(wf[t], d3, hacc[t][3]);
            }
        }
        {
            const float4 bv = ((const float4*)bp0)[lane];
            const float bt[4] = { bv.x, bv.y, bv.z, bv.w };
#pragma unroll
            for (int t = 0; t < 4; t++)
#pragma unroll
                for (int b = 0; b < 4; b++)
                    hacc[t][b] = gelu_prec(__fadd_rn(hacc[t][b], bt[t]));
        }

        float po[4][4];
#pragma unroll
        for (int b = 0; b < 4; b++)
#pragma unroll
            for (int k = 0; k < 4; k++) po[b][k] = 0.f;
#pragma unroll
        for (int t = 0; t < 4; t++) {
            const float4 w = ((const float4*)Wp1)[4 * lane + t];
            const float wf[4] = { w.x, w.y, w.z, w.w };
#pragma unroll
            for (int k = 0; k < 4; k++)
#pragma unroll
                for (int b = 0; b < 4; b++)
                    po[b][k] = __fmaf_rn(hacc[t][b], wf[k], po[b][k]);
        }
#pragma unroll
        for (int b = 0; b < 4; b++)
#pragma unroll
            for (int k = 0; k < 4; k++) {
                float v = po[b][k];
#pragma unroll
                for (int off = 32; off >= 1; off >>= 1)
                    v = __fadd_rn(v, __shfl_xor(v, off, 64));
                po[b][k] = v;
            }

        if (lane == 0) {
#pragma unroll
            for (int b = 0; b < 4; b++)
#pragma unroll
                for (int k = 0; k < 4; k++)
                    out[((size_t)b * NQRY + q) * 4 + k] = __fadd_rn(po[b][k], bp1[k]);
        }
        WSYNC();                         // protect decs region before next query's L1
    }
}

// ---------------------------------------------------------------------------
extern "C" void kernel_launch(void* const* d_in, const int* in_sizes, int n_in,
                              void* d_out, int out_size, void* d_ws, size_t ws_size,
                              hipStream_t stream) {
    const float* lat  = (const float*)d_in[0];
    const float* rnd  = (const float*)d_in[1];
    const float* qc   = (const float*)d_in[2];
    const int*   src0 = (const int*)d_in[3];
    const int*   qry0 = (const int*)d_in[4];
    const int*   src1 = (const int*)d_in[5];
    const int*   qry1 = (const int*)d_in[6];
    const float* Wk0 = (const float*)d_in[7],  *bk0 = (const float*)d_in[8];
    const float* Wk1 = (const float*)d_in[9],  *bk1 = (const float*)d_in[10];
    const float* Wk2 = (const float*)d_in[11], *bk2 = (const float*)d_in[12];
    const float* Wsw0 = (const float*)d_in[13], *bsw0 = (const float*)d_in[14];
    const float* Wsw1 = (const float*)d_in[15], *bsw1 = (const float*)d_in[16];
    const float* Wp0 = (const float*)d_in[17], *bp0 = (const float*)d_in[18];
    const float* Wp1 = (const float*)d_in[19], *bp1 = (const float*)d_in[20];

    const int E0 = in_sizes[3];
    const int E1 = in_sizes[5];

    // workspace: two bounds tables (lower_bound of every query id), 131080 B
    int* cnt0 = (int*)d_ws;
    int* cnt1 = cnt0 + (NQRY + 1);

    build_bounds<<<(E0 + 255) / 256, 256, 0, stream>>>(qry0, E0, cnt0);
    build_bounds<<<(E1 + 255) / 256, 256, 0, stream>>>(qry1, E1, cnt1);

    fused_kernel<<<NQRY / (QPW * WPB), WPB * 64, 0, stream>>>(
        lat, rnd, qc, src0, cnt0, src1, cnt1,
        Wk0, bk0, Wk1, bk1, Wk2, bk2,
        Wsw0, bsw0, Wsw1, bsw1, Wp0, bp0, Wp1, bp1,
        (float*)d_out);
}